// Round 2
// baseline (39916.159 us; speedup 1.0000x reference)
//
#include <hip/hip_runtime.h>
#include <hip/hip_bf16.h>
#include <math.h>

#define TENC 256
#define NI   6
#define LSTR 68   // LDS row stride in floats: 16B-aligned, breaks pow-2 bank stride

__device__ __forceinline__ float sigm_(float x) { return 1.0f / (1.0f + expf(-x)); }

__device__ __forceinline__ void load_row64(const float* p, float* d) {
#pragma unroll
    for (int c = 0; c < 16; ++c) {
        float4 v = *reinterpret_cast<const float4*>(p + 4 * c);
        d[4 * c + 0] = v.x; d[4 * c + 1] = v.y;
        d[4 * c + 2] = v.z; d[4 * c + 3] = v.w;
    }
}

// Computes 4 consecutive GRU outputs j0..j0+3 for one cell.
// Gate rows (PyTorch order): r=j, z=64+j, n=128+j. Weights are wave-uniform
// (j0 derived from readfirstlane'd wave id) -> scalar loads, FMA = v,s,v.
template<int KIN>
__device__ __forceinline__ void gru4(const float* __restrict__ Wih,
                                     const float* __restrict__ Whh,
                                     const float* __restrict__ bih,
                                     const float* __restrict__ bhh,
                                     const float* xin, const float* hc,
                                     int j0, float* hn)
{
    float ar[4], az[4], an[4], ah[4];
#pragma unroll
    for (int q = 0; q < 4; ++q) {
        int j = j0 + q;
        ar[q] = bih[j]       + bhh[j];        // r: bih_r + bhh_r folded
        az[q] = bih[64 + j]  + bhh[64 + j];   // z
        an[q] = bih[128 + j];                 // n (input part)
        ah[q] = bhh[128 + j];                 // n (hidden part, scaled by r)
    }
#pragma unroll
    for (int q = 0; q < 4; ++q) {
        int j = j0 + q;
#pragma unroll
        for (int k = 0; k < KIN; ++k) {
            ar[q] = fmaf(Wih[j * KIN + k],         xin[k], ar[q]);
            az[q] = fmaf(Wih[(64 + j) * KIN + k],  xin[k], az[q]);
            an[q] = fmaf(Wih[(128 + j) * KIN + k], xin[k], an[q]);
        }
    }
#pragma unroll
    for (int q = 0; q < 4; ++q) {
        int j = j0 + q;
#pragma unroll
        for (int k = 0; k < 64; ++k) {
            ar[q] = fmaf(Whh[j * 64 + k],         hc[k], ar[q]);
            az[q] = fmaf(Whh[(64 + j) * 64 + k],  hc[k], az[q]);
            ah[q] = fmaf(Whh[(128 + j) * 64 + k], hc[k], ah[q]);
        }
    }
#pragma unroll
    for (int q = 0; q < 4; ++q) {
        float r = sigm_(ar[q]);
        float z = sigm_(az[q]);
        float n = tanhf(fmaf(r, ah[q], an[q]));
        hn[q] = (1.0f - z) * n + z * hc[j0 + q];
    }
}

extern "C" __global__ void __launch_bounds__(512, 2)
ccseq_kernel(const float* __restrict__ x, const int* __restrict__ p_tlen,
             const float* __restrict__ eW0, const float* __restrict__ eU0,
             const float* __restrict__ eBi0, const float* __restrict__ eBh0,
             const float* __restrict__ eW1, const float* __restrict__ eU1,
             const float* __restrict__ eBi1, const float* __restrict__ eBh1,
             const float* __restrict__ dW0, const float* __restrict__ dU0,
             const float* __restrict__ dBi0, const float* __restrict__ dBh0,
             const float* __restrict__ dW1, const float* __restrict__ dU1,
             const float* __restrict__ dBi1, const float* __restrict__ dBh1,
             const float* __restrict__ Won, const float* __restrict__ bon,
             const float* __restrict__ Wcv, const float* __restrict__ bcv,
             float* __restrict__ out)
{
    // Lane = batch element; wave = hidden-unit slice (8 j's per wave).
    // LDS holds per-batch h0/h1 rows for cross-wave exchange only
    // (lane b exclusively touches row b; hazards are cross-wave -> barriers).
    __shared__ float sh0[64 * LSTR];
    __shared__ float sh1[64 * LSTR];

    const int lane = threadIdx.x & 63;
    const int wv   = __builtin_amdgcn_readfirstlane((int)(threadIdx.x >> 6)); // 0..7
    const int j0   = wv * 8;
    const int b    = blockIdx.x * 64 + lane;
    const int tlen = p_tlen[0];

    for (int i = threadIdx.x; i < 64 * LSTR; i += 512) { sh0[i] = 0.0f; sh1[i] = 0.0f; }
    __syncthreads();

    float* row0 = &sh0[lane * LSTR];
    float* row1 = &sh1[lane * LSTR];

    const float* xb = x + (size_t)b * (TENC * NI);

    // ---------------- encoder: 256 steps ----------------
    float xcur[NI];
#pragma unroll
    for (int i = 0; i < NI; ++i) xcur[i] = xb[i];

    for (int t = 0; t < TENC; ++t) {
        // prefetch next x (latency hidden behind this step's FMAs)
        float xnx[NI];
        const int tn = (t + 1 < TENC) ? (t + 1) : t;
#pragma unroll
        for (int i = 0; i < NI; ++i) xnx[i] = xb[tn * NI + i];

        float h0c[64];
        load_row64(row0, h0c);
        float hn[8];
        gru4<NI>(eW0, eU0, eBi0, eBh0, xcur, h0c, j0,     hn);
        gru4<NI>(eW0, eU0, eBi0, eBh0, xcur, h0c, j0 + 4, hn + 4);
        __syncthreads();  // all waves done reading h0
        *(float4*)(row0 + j0)     = make_float4(hn[0], hn[1], hn[2], hn[3]);
        *(float4*)(row0 + j0 + 4) = make_float4(hn[4], hn[5], hn[6], hn[7]);
        __syncthreads();  // new h0 visible

        float h0n[64], h1c[64];
        load_row64(row0, h0n);
        load_row64(row1, h1c);
        gru4<64>(eW1, eU1, eBi1, eBh1, h0n, h1c, j0,     hn);
        gru4<64>(eW1, eU1, eBi1, eBh1, h0n, h1c, j0 + 4, hn + 4);
        __syncthreads();  // all waves done reading h1
        *(float4*)(row1 + j0)     = make_float4(hn[0], hn[1], hn[2], hn[3]);
        *(float4*)(row1 + j0 + 4) = make_float4(hn[4], hn[5], hn[6], hn[7]);
        __syncthreads();  // new h1 visible

#pragma unroll
        for (int i = 0; i < NI; ++i) xcur[i] = xnx[i];
    }

    // ---------------- decoder: tlen steps ----------------
    float prev = 0.0f;
    for (int t = 0; t < tlen; ++t) {
        float h0c[64];
        load_row64(row0, h0c);
        float hn[8];
        gru4<1>(dW0, dU0, dBi0, dBh0, &prev, h0c, j0,     hn);
        gru4<1>(dW0, dU0, dBi0, dBh0, &prev, h0c, j0 + 4, hn + 4);
        __syncthreads();
        *(float4*)(row0 + j0)     = make_float4(hn[0], hn[1], hn[2], hn[3]);
        *(float4*)(row0 + j0 + 4) = make_float4(hn[4], hn[5], hn[6], hn[7]);
        __syncthreads();

        float h0n[64], h1c[64];
        load_row64(row0, h0n);
        load_row64(row1, h1c);
        gru4<64>(dW1, dU1, dBi1, dBh1, h0n, h1c, j0,     hn);
        gru4<64>(dW1, dU1, dBi1, dBh1, h0n, h1c, j0 + 4, hn + 4);
        __syncthreads();
        *(float4*)(row1 + j0)     = make_float4(hn[0], hn[1], hn[2], hn[3]);
        *(float4*)(row1 + j0 + 4) = make_float4(hn[4], hn[5], hn[6], hn[7]);
        __syncthreads();  // h1 complete -> heads may read full row

        float h1n[64];
        load_row64(row1, h1n);
        float cv = bcv[0], lg = bon[0];
#pragma unroll
        for (int k = 0; k < 64; ++k) {
            cv = fmaf(Wcv[k], h1n[k], cv);
            lg = fmaf(Won[k], h1n[k], lg);
        }
        // sigmoid(lg) > 0.5  <=>  lg > 0 (exact, monotone)
        const float gated = (lg > 0.0f) ? cv : 0.0f;
        prev = gated;
        if (wv == 0) out[(size_t)b * tlen + t] = gated;
    }
}

extern "C" void kernel_launch(void* const* d_in, const int* in_sizes, int n_in,
                              void* d_out, int out_size, void* d_ws, size_t ws_size,
                              hipStream_t stream)
{
    (void)n_in; (void)out_size; (void)d_ws; (void)ws_size;
    const float* x    = (const float*)d_in[0];
    const int*   tl   = (const int*)d_in[1];
    const float* eW0  = (const float*)d_in[2];
    const float* eU0  = (const float*)d_in[3];
    const float* eBi0 = (const float*)d_in[4];
    const float* eBh0 = (const float*)d_in[5];
    const float* eW1  = (const float*)d_in[6];
    const float* eU1  = (const float*)d_in[7];
    const float* eBi1 = (const float*)d_in[8];
    const float* eBh1 = (const float*)d_in[9];
    const float* dW0  = (const float*)d_in[10];
    const float* dU0  = (const float*)d_in[11];
    const float* dBi0 = (const float*)d_in[12];
    const float* dBh0 = (const float*)d_in[13];
    const float* dW1  = (const float*)d_in[14];
    const float* dU1  = (const float*)d_in[15];
    const float* dBi1 = (const float*)d_in[16];
    const float* dBh1 = (const float*)d_in[17];
    const float* Won  = (const float*)d_in[18];
    const float* bon  = (const float*)d_in[19];
    const float* Wcv  = (const float*)d_in[20];
    const float* bcv  = (const float*)d_in[21];

    const int B    = in_sizes[0] / (TENC * NI);  // 16384
    const int nblk = B / 64;                     // 256 blocks, 1 per CU

    ccseq_kernel<<<dim3(nblk), dim3(512), 0, stream>>>(
        x, tl, eW0, eU0, eBi0, eBh0, eW1, eU1, eBi1, eBh1,
        dW0, dU0, dBi0, dBh0, dW1, dU1, dBi1, dBh1,
        Won, bon, Wcv, bcv, (float*)d_out);
}

// Round 3
// 32938.699 us; speedup vs baseline: 1.2118x; 1.2118x over previous
//
#include <hip/hip_runtime.h>
#include <hip/hip_bf16.h>
#include <math.h>

#define TENC 256
#define NI   6
#define LSTR 68   // floats; 68 % 8 == 4 -> conflict-free ds_read_b128 phases, 16B aligned

__device__ __forceinline__ float sigm_(float x) { return 1.0f / (1.0f + expf(-x)); }

// ---- GRU cell, input vector in REGISTERS (encoder L0: KIN=6, decoder L0: KIN=1) ----
// Computes 8 hidden units j0..j0+7 for this wave. All local arrays constant-indexed.
template<int KIN>
__device__ __forceinline__ void gru_regx(const float* __restrict__ Wih,
                                         const float* __restrict__ Whh,
                                         const float* __restrict__ bih,
                                         const float* __restrict__ bhh,
                                         const float* xin,      // KIN regs
                                         const float* rowH,     // LDS: old h row (this lane)
                                         int j0, float* hn)     // 8 outputs
{
    float accr[8], accz[8], accnx[8], accnh[8];
#pragma unroll
    for (int q = 0; q < 8; ++q) {
        int j = j0 + q;
        accr[q]  = bih[j]       + bhh[j];
        accz[q]  = bih[64 + j]  + bhh[64 + j];
        accnx[q] = bih[128 + j];
        accnh[q] = bhh[128 + j];
    }
#pragma unroll
    for (int q = 0; q < 8; ++q) {
        int j = j0 + q;
#pragma unroll
        for (int k = 0; k < KIN; ++k) {
            accr[q]  = fmaf(Wih[j * KIN + k],         xin[k], accr[q]);
            accz[q]  = fmaf(Wih[(64 + j) * KIN + k],  xin[k], accz[q]);
            accnx[q] = fmaf(Wih[(128 + j) * KIN + k], xin[k], accnx[q]);
        }
    }
#pragma unroll
    for (int kc = 0; kc < 64; kc += 4) {
        float4 h4 = *(const float4*)(rowH + kc);
        float hv[4] = {h4.x, h4.y, h4.z, h4.w};
#pragma unroll
        for (int q = 0; q < 8; ++q) {
            int j = j0 + q;
#pragma unroll
            for (int kk = 0; kk < 4; ++kk) {
                accr[q]  = fmaf(Whh[j * 64 + kc + kk],         hv[kk], accr[q]);
                accz[q]  = fmaf(Whh[(64 + j) * 64 + kc + kk],  hv[kk], accz[q]);
                accnh[q] = fmaf(Whh[(128 + j) * 64 + kc + kk], hv[kk], accnh[q]);
            }
        }
    }
    float4 ho0 = *(const float4*)(rowH + j0);      // wave-uniform offset: no dyn reg index
    float4 ho1 = *(const float4*)(rowH + j0 + 4);
    float hold[8] = {ho0.x, ho0.y, ho0.z, ho0.w, ho1.x, ho1.y, ho1.z, ho1.w};
#pragma unroll
    for (int q = 0; q < 8; ++q) {
        float r = sigm_(accr[q]);
        float z = sigm_(accz[q]);
        float n = tanhf(fmaf(r, accnh[q], accnx[q]));
        hn[q] = fmaf(z, hold[q] - n, n);           // (1-z)n + z h
    }
}

// ---- GRU cell, input vector in LDS (layer 1: x = h0_new row) ----
__device__ __forceinline__ void gru_ldsx(const float* __restrict__ Wih,
                                         const float* __restrict__ Whh,
                                         const float* __restrict__ bih,
                                         const float* __restrict__ bhh,
                                         const float* rowX,     // LDS: h0_new row
                                         const float* rowH,     // LDS: h1_old row
                                         int j0, float* hn)
{
    float accr[8], accz[8], accnx[8], accnh[8];
#pragma unroll
    for (int q = 0; q < 8; ++q) {
        int j = j0 + q;
        accr[q]  = bih[j]       + bhh[j];
        accz[q]  = bih[64 + j]  + bhh[64 + j];
        accnx[q] = bih[128 + j];
        accnh[q] = bhh[128 + j];
    }
#pragma unroll
    for (int kc = 0; kc < 64; kc += 4) {
        float4 x4 = *(const float4*)(rowX + kc);
        float4 h4 = *(const float4*)(rowH + kc);
        float xv[4] = {x4.x, x4.y, x4.z, x4.w};
        float hv[4] = {h4.x, h4.y, h4.z, h4.w};
#pragma unroll
        for (int q = 0; q < 8; ++q) {
            int j = j0 + q;
#pragma unroll
            for (int kk = 0; kk < 4; ++kk) {
                accr[q]  = fmaf(Wih[j * 64 + kc + kk],         xv[kk], accr[q]);
                accz[q]  = fmaf(Wih[(64 + j) * 64 + kc + kk],  xv[kk], accz[q]);
                accnx[q] = fmaf(Wih[(128 + j) * 64 + kc + kk], xv[kk], accnx[q]);
                accr[q]  = fmaf(Whh[j * 64 + kc + kk],         hv[kk], accr[q]);
                accz[q]  = fmaf(Whh[(64 + j) * 64 + kc + kk],  hv[kk], accz[q]);
                accnh[q] = fmaf(Whh[(128 + j) * 64 + kc + kk], hv[kk], accnh[q]);
            }
        }
    }
    float4 ho0 = *(const float4*)(rowH + j0);
    float4 ho1 = *(const float4*)(rowH + j0 + 4);
    float hold[8] = {ho0.x, ho0.y, ho0.z, ho0.w, ho1.x, ho1.y, ho1.z, ho1.w};
#pragma unroll
    for (int q = 0; q < 8; ++q) {
        float r = sigm_(accr[q]);
        float z = sigm_(accz[q]);
        float n = tanhf(fmaf(r, accnh[q], accnx[q]));
        hn[q] = fmaf(z, hold[q] - n, n);
    }
}

extern "C" __global__ void __launch_bounds__(512, 2)
ccseq_kernel(const float* __restrict__ x, const int* __restrict__ p_tlen,
             const float* __restrict__ eW0, const float* __restrict__ eU0,
             const float* __restrict__ eBi0, const float* __restrict__ eBh0,
             const float* __restrict__ eW1, const float* __restrict__ eU1,
             const float* __restrict__ eBi1, const float* __restrict__ eBh1,
             const float* __restrict__ dW0, const float* __restrict__ dU0,
             const float* __restrict__ dBi0, const float* __restrict__ dBh0,
             const float* __restrict__ dW1, const float* __restrict__ dU1,
             const float* __restrict__ dBi1, const float* __restrict__ dBh1,
             const float* __restrict__ Won, const float* __restrict__ bon,
             const float* __restrict__ Wcv, const float* __restrict__ bcv,
             float* __restrict__ out)
{
    // lane = batch, wave = 8-hidden-unit slice. Double-buffered h in LDS:
    // step reads r*, writes w*, 2 barriers/step.
    __shared__ float sA0[64 * LSTR], sA1[64 * LSTR];
    __shared__ float sB0[64 * LSTR], sB1[64 * LSTR];

    const int lane = threadIdx.x & 63;
    const int wv   = __builtin_amdgcn_readfirstlane((int)(threadIdx.x >> 6)); // 0..7
    const int j0   = wv * 8;
    const int b    = blockIdx.x * 64 + lane;
    const int tlen = p_tlen[0];

    for (int i = threadIdx.x; i < 64 * LSTR; i += 512) {
        sA0[i] = 0.0f; sA1[i] = 0.0f; sB0[i] = 0.0f; sB1[i] = 0.0f;
    }
    __syncthreads();

    const int ro = lane * LSTR;
    float* r0 = sA0 + ro; float* r1 = sA1 + ro;   // read buffers (h_old)
    float* w0 = sB0 + ro; float* w1 = sB1 + ro;   // write buffers (h_new)

    const float* xb = x + (size_t)b * (TENC * NI);

    // ---------------- encoder ----------------
    float xcur[NI];
#pragma unroll
    for (int i = 0; i < NI; ++i) xcur[i] = xb[i];

    for (int t = 0; t < TENC; ++t) {
        float xnx[NI];
        const int tn = (t + 1 < TENC) ? (t + 1) : t;
#pragma unroll
        for (int i = 0; i < NI; ++i) xnx[i] = xb[tn * NI + i];

        float hn[8];
        gru_regx<NI>(eW0, eU0, eBi0, eBh0, xcur, r0, j0, hn);
        *(float4*)(w0 + j0)     = make_float4(hn[0], hn[1], hn[2], hn[3]);
        *(float4*)(w0 + j0 + 4) = make_float4(hn[4], hn[5], hn[6], hn[7]);
        __syncthreads();                       // h0_new published

        gru_ldsx(eW1, eU1, eBi1, eBh1, w0, r1, j0, hn);
        *(float4*)(w1 + j0)     = make_float4(hn[0], hn[1], hn[2], hn[3]);
        *(float4*)(w1 + j0 + 4) = make_float4(hn[4], hn[5], hn[6], hn[7]);
        __syncthreads();                       // h1_new published; old bufs free

        { float* tp = r0; r0 = w0; w0 = tp; }
        { float* tp = r1; r1 = w1; w1 = tp; }
#pragma unroll
        for (int i = 0; i < NI; ++i) xcur[i] = xnx[i];
    }

    // ---------------- decoder ----------------
    float prev = 0.0f;
    for (int t = 0; t < tlen; ++t) {
        float hn[8];
        gru_regx<1>(dW0, dU0, dBi0, dBh0, &prev, r0, j0, hn);
        *(float4*)(w0 + j0)     = make_float4(hn[0], hn[1], hn[2], hn[3]);
        *(float4*)(w0 + j0 + 4) = make_float4(hn[4], hn[5], hn[6], hn[7]);
        __syncthreads();

        gru_ldsx(dW1, dU1, dBi1, dBh1, w0, r1, j0, hn);
        *(float4*)(w1 + j0)     = make_float4(hn[0], hn[1], hn[2], hn[3]);
        *(float4*)(w1 + j0 + 4) = make_float4(hn[4], hn[5], hn[6], hn[7]);
        __syncthreads();                       // full h1_new readable

        // heads (all waves redundantly; wv==0 stores)
        float cv = bcv[0], lg = bon[0];
#pragma unroll
        for (int kc = 0; kc < 64; kc += 4) {
            float4 h4 = *(const float4*)(w1 + kc);
            float hv[4] = {h4.x, h4.y, h4.z, h4.w};
#pragma unroll
            for (int kk = 0; kk < 4; ++kk) {
                cv = fmaf(Wcv[kc + kk], hv[kk], cv);
                lg = fmaf(Won[kc + kk], hv[kk], lg);
            }
        }
        const float gated = (lg > 0.0f) ? cv : 0.0f;   // sigmoid(lg)>0.5 <=> lg>0
        prev = gated;
        if (wv == 0) out[(size_t)b * tlen + t] = gated;

        { float* tp = r0; r0 = w0; w0 = tp; }
        { float* tp = r1; r1 = w1; w1 = tp; }
    }
}

extern "C" void kernel_launch(void* const* d_in, const int* in_sizes, int n_in,
                              void* d_out, int out_size, void* d_ws, size_t ws_size,
                              hipStream_t stream)
{
    (void)n_in; (void)out_size; (void)d_ws; (void)ws_size;
    const float* x    = (const float*)d_in[0];
    const int*   tl   = (const int*)d_in[1];
    const float* eW0  = (const float*)d_in[2];
    const float* eU0  = (const float*)d_in[3];
    const float* eBi0 = (const float*)d_in[4];
    const float* eBh0 = (const float*)d_in[5];
    const float* eW1  = (const float*)d_in[6];
    const float* eU1  = (const float*)d_in[7];
    const float* eBi1 = (const float*)d_in[8];
    const float* eBh1 = (const float*)d_in[9];
    const float* dW0  = (const float*)d_in[10];
    const float* dU0  = (const float*)d_in[11];
    const float* dBi0 = (const float*)d_in[12];
    const float* dBh0 = (const float*)d_in[13];
    const float* dW1  = (const float*)d_in[14];
    const float* dU1  = (const float*)d_in[15];
    const float* dBi1 = (const float*)d_in[16];
    const float* dBh1 = (const float*)d_in[17];
    const float* Won  = (const float*)d_in[18];
    const float* bon  = (const float*)d_in[19];
    const float* Wcv  = (const float*)d_in[20];
    const float* bcv  = (const float*)d_in[21];

    const int B    = in_sizes[0] / (TENC * NI);  // 16384
    const int nblk = B / 64;                     // 256 blocks

    ccseq_kernel<<<dim3(nblk), dim3(512), 0, stream>>>(
        x, tl, eW0, eU0, eBi0, eBh0, eW1, eU1, eBi1, eBh1,
        dW0, dU0, dBi0, dBh0, dW1, dU1, dBi1, dBh1,
        Won, bon, Wcv, bcv, (float*)d_out);
}

// Round 4
// 17755.899 us; speedup vs baseline: 2.2481x; 1.8551x over previous
//
#include <hip/hip_runtime.h>
#include <hip/hip_bf16.h>
#include <math.h>

#define TENC 256
#define NIE  6      // encoder layer-0 input size
#define LH   68     // h row stride (floats): %4==0 for b128 align; 2-way bank alias = free

__device__ __forceinline__ float sigm_(float x) { return 1.0f / (1.0f + expf(-x)); }

// ---- LDS (static). Total 142,864 B <= 160 KiB -> 1 block/CU. ----
// W1/U1 layout: [(j*3+g)*64 + k]  (j-major so a wave's slice is uniform-addr rows)
// W0  layout: [(j*3+g)*8 + k]   (k < NI, padded to 8)
__shared__ float sW1[12288];
__shared__ float sU1[12288];
__shared__ float sW0[1536];
__shared__ float sBi0[192], sBh0[192], sBi1[192], sBh1[192];
__shared__ float sHd[132];          // [0:64) Wcv, [64:128) Won, 128=bcv, 129=bon
__shared__ float sh0[64 * LH];
__shared__ float sh1[64 * LH];

// Copy one phase's weights into LDS. NI_ = layer-0 input width (6 or 1).
template<int NI_>
__device__ __forceinline__ void load_phase(const float* __restrict__ W0,
                                           const float* __restrict__ U0_unused,
                                           const float* __restrict__ W1,
                                           const float* __restrict__ U1,
                                           const float* __restrict__ bi0,
                                           const float* __restrict__ bh0,
                                           const float* __restrict__ bi1,
                                           const float* __restrict__ bh1)
{
    const int tid = threadIdx.x;
    for (int s = tid; s < 12288; s += 512) {          // coalesced read, scattered LDS write
        int k = s & 63, row = s >> 6;
        int g = row >> 6, j = row & 63;
        int d = ((j * 3 + g) << 6) | k;
        sW1[d] = W1[s];
        sU1[d] = U1[s];
    }
    for (int s = tid; s < 192 * NI_; s += 512) {
        int r = s / NI_, k = s - r * NI_;             // NI_ is compile-time
        int g = r >> 6, j = r & 63;
        sW0[(j * 3 + g) * 8 + k] = W0[s];
    }
    for (int s = tid; s < 192; s += 512) {
        sBi0[s] = bi0[s]; sBh0[s] = bh0[s];
        sBi1[s] = bi1[s]; sBh1[s] = bh1[s];
    }
}

// ---- layer 0: input x in registers (NI_ wide), W0 from LDS, U0 from GLOBAL ----
template<int NI_>
__device__ __forceinline__ void layer0(const float* __restrict__ U0,
                                       const float* xin, const float* h0row,
                                       int j0, float* hn)
{
    float ar[8], az[8], an[8], ah[8];
#pragma unroll
    for (int q = 0; q < 8; ++q) {
        int j = j0 + q;
        ar[q] = sBi0[j]       + sBh0[j];
        az[q] = sBi0[64 + j]  + sBh0[64 + j];
        an[q] = sBi0[128 + j];
        ah[q] = sBh0[128 + j];
    }
#pragma unroll
    for (int q = 0; q < 8; ++q) {
        int j = j0 + q;
#pragma unroll
        for (int k = 0; k < NI_; ++k) {
            ar[q] = fmaf(sW0[(j * 3 + 0) * 8 + k], xin[k], ar[q]);
            az[q] = fmaf(sW0[(j * 3 + 1) * 8 + k], xin[k], az[q]);
            an[q] = fmaf(sW0[(j * 3 + 2) * 8 + k], xin[k], an[q]);
        }
    }
#pragma unroll 4
    for (int kc = 0; kc < 64; kc += 4) {
        float4 h4 = *(const float4*)(h0row + kc);
        float hv[4] = {h4.x, h4.y, h4.z, h4.w};
#pragma unroll
        for (int q = 0; q < 8; ++q) {
            int j = j0 + q;
            float4 wr = *(const float4*)(U0 + (j)*64 + kc);          // rows g*64+j
            float4 wz = *(const float4*)(U0 + (64 + j) * 64 + kc);
            float4 wn = *(const float4*)(U0 + (128 + j) * 64 + kc);
            ar[q] = fmaf(wr.x, hv[0], ar[q]); ar[q] = fmaf(wr.y, hv[1], ar[q]);
            ar[q] = fmaf(wr.z, hv[2], ar[q]); ar[q] = fmaf(wr.w, hv[3], ar[q]);
            az[q] = fmaf(wz.x, hv[0], az[q]); az[q] = fmaf(wz.y, hv[1], az[q]);
            az[q] = fmaf(wz.z, hv[2], az[q]); az[q] = fmaf(wz.w, hv[3], az[q]);
            ah[q] = fmaf(wn.x, hv[0], ah[q]); ah[q] = fmaf(wn.y, hv[1], ah[q]);
            ah[q] = fmaf(wn.z, hv[2], ah[q]); ah[q] = fmaf(wn.w, hv[3], ah[q]);
        }
    }
    float4 ho0 = *(const float4*)(h0row + j0);
    float4 ho1 = *(const float4*)(h0row + j0 + 4);
    float hold[8] = {ho0.x, ho0.y, ho0.z, ho0.w, ho1.x, ho1.y, ho1.z, ho1.w};
#pragma unroll
    for (int q = 0; q < 8; ++q) {
        float r = sigm_(ar[q]);
        float z = sigm_(az[q]);
        float n = tanhf(fmaf(r, ah[q], an[q]));
        hn[q] = fmaf(z, hold[q] - n, n);
    }
}

// ---- layer 1: x = h0row (LDS), W1/U1 from LDS (uniform-addr broadcast reads) ----
__device__ __forceinline__ void layer1(const float* xrow, const float* h1row,
                                       int j0, float* hn)
{
    float ar[8], az[8], an[8], ah[8];
#pragma unroll
    for (int q = 0; q < 8; ++q) {
        int j = j0 + q;
        ar[q] = sBi1[j]       + sBh1[j];
        az[q] = sBi1[64 + j]  + sBh1[64 + j];
        an[q] = sBi1[128 + j];
        ah[q] = sBh1[128 + j];
    }
#pragma unroll 4
    for (int kc = 0; kc < 64; kc += 4) {
        float4 x4 = *(const float4*)(xrow + kc);
        float4 h4 = *(const float4*)(h1row + kc);
        float xv[4] = {x4.x, x4.y, x4.z, x4.w};
        float hv[4] = {h4.x, h4.y, h4.z, h4.w};
#pragma unroll
        for (int q = 0; q < 8; ++q) {
            int j = j0 + q;
            float4 wr = *(const float4*)(&sW1[((j * 3 + 0) << 6) + kc]);
            float4 wz = *(const float4*)(&sW1[((j * 3 + 1) << 6) + kc]);
            float4 wn = *(const float4*)(&sW1[((j * 3 + 2) << 6) + kc]);
            float4 ur = *(const float4*)(&sU1[((j * 3 + 0) << 6) + kc]);
            float4 uz = *(const float4*)(&sU1[((j * 3 + 1) << 6) + kc]);
            float4 un = *(const float4*)(&sU1[((j * 3 + 2) << 6) + kc]);
            ar[q] = fmaf(wr.x, xv[0], ar[q]); ar[q] = fmaf(wr.y, xv[1], ar[q]);
            ar[q] = fmaf(wr.z, xv[2], ar[q]); ar[q] = fmaf(wr.w, xv[3], ar[q]);
            az[q] = fmaf(wz.x, xv[0], az[q]); az[q] = fmaf(wz.y, xv[1], az[q]);
            az[q] = fmaf(wz.z, xv[2], az[q]); az[q] = fmaf(wz.w, xv[3], az[q]);
            an[q] = fmaf(wn.x, xv[0], an[q]); an[q] = fmaf(wn.y, xv[1], an[q]);
            an[q] = fmaf(wn.z, xv[2], an[q]); an[q] = fmaf(wn.w, xv[3], an[q]);
            ar[q] = fmaf(ur.x, hv[0], ar[q]); ar[q] = fmaf(ur.y, hv[1], ar[q]);
            ar[q] = fmaf(ur.z, hv[2], ar[q]); ar[q] = fmaf(ur.w, hv[3], ar[q]);
            az[q] = fmaf(uz.x, hv[0], az[q]); az[q] = fmaf(uz.y, hv[1], az[q]);
            az[q] = fmaf(uz.z, hv[2], az[q]); az[q] = fmaf(uz.w, hv[3], az[q]);
            ah[q] = fmaf(un.x, hv[0], ah[q]); ah[q] = fmaf(un.y, hv[1], ah[q]);
            ah[q] = fmaf(un.z, hv[2], ah[q]); ah[q] = fmaf(un.w, hv[3], ah[q]);
        }
    }
    float4 ho0 = *(const float4*)(h1row + j0);
    float4 ho1 = *(const float4*)(h1row + j0 + 4);
    float hold[8] = {ho0.x, ho0.y, ho0.z, ho0.w, ho1.x, ho1.y, ho1.z, ho1.w};
#pragma unroll
    for (int q = 0; q < 8; ++q) {
        float r = sigm_(ar[q]);
        float z = sigm_(az[q]);
        float n = tanhf(fmaf(r, ah[q], an[q]));
        hn[q] = fmaf(z, hold[q] - n, n);
    }
}

extern "C" __global__ void __launch_bounds__(512, 2)
ccseq_kernel(const float* __restrict__ x, const int* __restrict__ p_tlen,
             const float* __restrict__ eW0, const float* __restrict__ eU0,
             const float* __restrict__ eBi0, const float* __restrict__ eBh0,
             const float* __restrict__ eW1, const float* __restrict__ eU1,
             const float* __restrict__ eBi1, const float* __restrict__ eBh1,
             const float* __restrict__ dW0, const float* __restrict__ dU0,
             const float* __restrict__ dBi0, const float* __restrict__ dBh0,
             const float* __restrict__ dW1, const float* __restrict__ dU1,
             const float* __restrict__ dBi1, const float* __restrict__ dBh1,
             const float* __restrict__ Won, const float* __restrict__ bon,
             const float* __restrict__ Wcv, const float* __restrict__ bcv,
             float* __restrict__ out)
{
    const int tid  = threadIdx.x;
    const int lane = tid & 63;
    const int wv   = __builtin_amdgcn_readfirstlane((int)(tid >> 6)); // 0..7
    const int j0   = wv * 8;
    const int b    = blockIdx.x * 64 + lane;
    const int tlen = p_tlen[0];

    // heads (persist across both phases)
    if (tid < 64) { sHd[tid] = Wcv[tid]; sHd[64 + tid] = Won[tid]; }
    if (tid == 128) { sHd[128] = bcv[0]; sHd[129] = bon[0]; }
    // zero h state
    for (int i = tid; i < 64 * LH; i += 512) { sh0[i] = 0.0f; sh1[i] = 0.0f; }
    // encoder weights -> LDS
    load_phase<NIE>(eW0, eU0, eW1, eU1, eBi0, eBh0, eBi1, eBh1);
    __syncthreads();

    float* h0row = &sh0[lane * LH];
    float* h1row = &sh1[lane * LH];
    const float* xb = x + (size_t)b * (TENC * NIE);

    // ---------------- encoder ----------------
    float xcur[NIE];
#pragma unroll
    for (int i = 0; i < NIE; ++i) xcur[i] = xb[i];

    for (int t = 0; t < TENC; ++t) {
        float xnx[NIE];
        const int tn = (t + 1 < TENC) ? (t + 1) : t;
#pragma unroll
        for (int i = 0; i < NIE; ++i) xnx[i] = xb[tn * NIE + i];

        float hn[8];
        layer0<NIE>(eU0, xcur, h0row, j0, hn);
        __syncthreads();                                 // all h0 reads done
        *(float4*)(h0row + j0)     = make_float4(hn[0], hn[1], hn[2], hn[3]);
        *(float4*)(h0row + j0 + 4) = make_float4(hn[4], hn[5], hn[6], hn[7]);
        __syncthreads();                                 // h0_new visible

        layer1(h0row, h1row, j0, hn);
        __syncthreads();                                 // all h1 reads done
        *(float4*)(h1row + j0)     = make_float4(hn[0], hn[1], hn[2], hn[3]);
        *(float4*)(h1row + j0 + 4) = make_float4(hn[4], hn[5], hn[6], hn[7]);
        __syncthreads();                                 // h1_new visible

#pragma unroll
        for (int i = 0; i < NIE; ++i) xcur[i] = xnx[i];
    }

    // ---------------- swap weights to decoder set ----------------
    load_phase<1>(dW0, dU0, dW1, dU1, dBi0, dBh0, dBi1, dBh1);
    __syncthreads();

    // ---------------- decoder ----------------
    float prev = 0.0f;
    for (int t = 0; t < tlen; ++t) {
        float hn[8];
        layer0<1>(dU0, &prev, h0row, j0, hn);
        __syncthreads();
        *(float4*)(h0row + j0)     = make_float4(hn[0], hn[1], hn[2], hn[3]);
        *(float4*)(h0row + j0 + 4) = make_float4(hn[4], hn[5], hn[6], hn[7]);
        __syncthreads();

        layer1(h0row, h1row, j0, hn);
        __syncthreads();
        *(float4*)(h1row + j0)     = make_float4(hn[0], hn[1], hn[2], hn[3]);
        *(float4*)(h1row + j0 + 4) = make_float4(hn[4], hn[5], hn[6], hn[7]);
        __syncthreads();                                 // full h1_new readable

        // heads (all waves redundantly; wave 0 stores)
        float cv = sHd[128], lg = sHd[129];
#pragma unroll 4
        for (int kc = 0; kc < 64; kc += 4) {
            float4 h4 = *(const float4*)(h1row + kc);
            float hv[4] = {h4.x, h4.y, h4.z, h4.w};
#pragma unroll
            for (int kk = 0; kk < 4; ++kk) {
                cv = fmaf(sHd[kc + kk],      hv[kk], cv);
                lg = fmaf(sHd[64 + kc + kk], hv[kk], lg);
            }
        }
        const float gated = (lg > 0.0f) ? cv : 0.0f;     // sigmoid(lg)>0.5 <=> lg>0
        prev = gated;
        if (wv == 0) out[(size_t)b * tlen + t] = gated;
    }
}

extern "C" void kernel_launch(void* const* d_in, const int* in_sizes, int n_in,
                              void* d_out, int out_size, void* d_ws, size_t ws_size,
                              hipStream_t stream)
{
    (void)n_in; (void)out_size; (void)d_ws; (void)ws_size;
    const float* x    = (const float*)d_in[0];
    const int*   tl   = (const int*)d_in[1];
    const float* eW0  = (const float*)d_in[2];
    const float* eU0  = (const float*)d_in[3];
    const float* eBi0 = (const float*)d_in[4];
    const float* eBh0 = (const float*)d_in[5];
    const float* eW1  = (const float*)d_in[6];
    const float* eU1  = (const float*)d_in[7];
    const float* eBi1 = (const float*)d_in[8];
    const float* eBh1 = (const float*)d_in[9];
    const float* dW0  = (const float*)d_in[10];
    const float* dU0  = (const float*)d_in[11];
    const float* dBi0 = (const float*)d_in[12];
    const float* dBh0 = (const float*)d_in[13];
    const float* dW1  = (const float*)d_in[14];
    const float* dU1  = (const float*)d_in[15];
    const float* dBi1 = (const float*)d_in[16];
    const float* dBh1 = (const float*)d_in[17];
    const float* Won  = (const float*)d_in[18];
    const float* bon  = (const float*)d_in[19];
    const float* Wcv  = (const float*)d_in[20];
    const float* bcv  = (const float*)d_in[21];

    const int B    = in_sizes[0] / (TENC * NIE);  // 16384
    const int nblk = B / 64;                      // 256 blocks, 1/CU

    ccseq_kernel<<<dim3(nblk), dim3(512), 0, stream>>>(
        x, tl, eW0, eU0, eBi0, eBh0, eW1, eU1, eBi1, eBh1,
        dW0, dU0, dBi0, dBh0, dW1, dU1, dBi1, dBh1,
        Won, bon, Wcv, bcv, (float*)d_out);
}

// Round 6
// 9693.583 us; speedup vs baseline: 4.1178x; 1.8317x over previous
//
#include <hip/hip_runtime.h>
#include <math.h>

#define TENC 256
#define NIE  6
#define LH   68    // h row stride (floats): 16B-aligned rows, 2-way bank alias = free
#define WSTR 68    // weight row stride: jg-offsets land on banks {0,24,16,8} = conflict-free

// ---- LDS: 2*52224 + 528 + 2*17408 = 139,792 B ----
__shared__ float sW1[192 * WSTR];   // [(j*3+g)*WSTR + k]
__shared__ float sU1[192 * WSTR];
__shared__ float sHd[132];          // [0:64) Wcv, [64:128) Won
__shared__ float sh0[64 * LH];
__shared__ float sh1[64 * LH];

__device__ __forceinline__ float sigm_(float x) { return 1.0f / (1.0f + expf(-x)); }

__device__ __forceinline__ void fma4(float& acc, const float4& a, const float4& b) {
    acc = fmaf(a.x, b.x, acc);
    acc = fmaf(a.y, b.y, acc);
    acc = fmaf(a.z, b.z, acc);
    acc = fmaf(a.w, b.w, acc);
}

__device__ __forceinline__ void stage_w1(const float* __restrict__ W1,
                                         const float* __restrict__ U1) {
    for (int s = threadIdx.x; s < 12288; s += 512) {
        int k = s & 63, row = s >> 6;          // row = g*64 + j (global layout)
        int g = row >> 6, j = row & 63;
        int d = (j * 3 + g) * WSTR + k;        // j-major in LDS
        sW1[d] = W1[s];
        sU1[d] = U1[s];
    }
}

// layer 0: W0 in regs, U0 from global (L2-hot), h from sh0. 2 j's x 4 batches.
template<int KIN>
__device__ __forceinline__ void layer0_c(const float* __restrict__ U0,
                                         const float* w0r, const float* w0z,
                                         const float* w0n,          // [2*KIN] regs
                                         const float* xin,          // [4*KIN] regs
                                         const float* b_r, const float* b_z,
                                         const float* b_nx, const float* b_nh,
                                         int jB, int bl, float hn[2][4])
{
    float ar[2][4], az[2][4], anx[2][4], anh[2][4];
#pragma unroll
    for (int g = 0; g < 4; ++g) {
#pragma unroll
        for (int jj = 0; jj < 2; ++jj) {
            ar[jj][g] = b_r[jj]; az[jj][g] = b_z[jj];
            anx[jj][g] = b_nx[jj]; anh[jj][g] = b_nh[jj];
        }
    }
#pragma unroll
    for (int jj = 0; jj < 2; ++jj)
#pragma unroll
        for (int g = 0; g < 4; ++g)
#pragma unroll
            for (int k = 0; k < KIN; ++k) {
                ar[jj][g]  = fmaf(w0r[jj * KIN + k], xin[g * KIN + k], ar[jj][g]);
                az[jj][g]  = fmaf(w0z[jj * KIN + k], xin[g * KIN + k], az[jj][g]);
                anx[jj][g] = fmaf(w0n[jj * KIN + k], xin[g * KIN + k], anx[jj][g]);
            }
    const float* u0 = U0 + (size_t)jB * 64;
    const float* u1 = U0 + (size_t)(jB + 1) * 64;
    const float* hr0 = sh0 + bl * LH;
#pragma unroll 2
    for (int kc = 0; kc < 64; kc += 4) {
        float4 hv[4];
#pragma unroll
        for (int g = 0; g < 4; ++g)
            hv[g] = *(const float4*)(hr0 + g * (16 * LH) + kc);
        float4 r0 = *(const float4*)(u0 + kc);
        float4 z0 = *(const float4*)(u0 + 4096 + kc);
        float4 n0 = *(const float4*)(u0 + 8192 + kc);
        float4 r1 = *(const float4*)(u1 + kc);
        float4 z1 = *(const float4*)(u1 + 4096 + kc);
        float4 n1 = *(const float4*)(u1 + 8192 + kc);
#pragma unroll
        for (int g = 0; g < 4; ++g) {
            fma4(ar[0][g], r0, hv[g]); fma4(az[0][g], z0, hv[g]); fma4(anh[0][g], n0, hv[g]);
            fma4(ar[1][g], r1, hv[g]); fma4(az[1][g], z1, hv[g]); fma4(anh[1][g], n1, hv[g]);
        }
    }
#pragma unroll
    for (int g = 0; g < 4; ++g) {
        float2 ho = *(const float2*)(sh0 + (bl + 16 * g) * LH + jB);
        float hold[2] = {ho.x, ho.y};
#pragma unroll
        for (int jj = 0; jj < 2; ++jj) {
            float r = sigm_(ar[jj][g]);
            float z = sigm_(az[jj][g]);
            float n = tanhf(fmaf(r, anh[jj][g], anx[jj][g]));
            hn[jj][g] = fmaf(z, hold[jj] - n, n);
        }
    }
}

// layer 1: x = sh0 rows, h = sh1 rows, W1/U1 from LDS. 2 j's x 4 batches.
__device__ __forceinline__ void layer1_c(const float* b_r, const float* b_z,
                                         const float* b_nx, const float* b_nh,
                                         int jB, int bl, float hn[2][4])
{
    float ar[2][4], az[2][4], anx[2][4], anh[2][4];
#pragma unroll
    for (int g = 0; g < 4; ++g) {
#pragma unroll
        for (int jj = 0; jj < 2; ++jj) {
            ar[jj][g] = b_r[jj]; az[jj][g] = b_z[jj];
            anx[jj][g] = b_nx[jj]; anh[jj][g] = b_nh[jj];
        }
    }
    const float* wb0 = sW1 + (jB * 3) * WSTR;
    const float* wb1 = sW1 + ((jB + 1) * 3) * WSTR;
    const float* ub0 = sU1 + (jB * 3) * WSTR;
    const float* ub1 = sU1 + ((jB + 1) * 3) * WSTR;
    const float* xr0 = sh0 + bl * LH;
    const float* hr0 = sh1 + bl * LH;
#pragma unroll 2
    for (int kc = 0; kc < 64; kc += 4) {
        float4 xv[4], hv[4];
#pragma unroll
        for (int g = 0; g < 4; ++g) {
            xv[g] = *(const float4*)(xr0 + g * (16 * LH) + kc);
            hv[g] = *(const float4*)(hr0 + g * (16 * LH) + kc);
        }
        float4 wr0 = *(const float4*)(wb0 + kc);
        float4 wz0 = *(const float4*)(wb0 + WSTR + kc);
        float4 wn0 = *(const float4*)(wb0 + 2 * WSTR + kc);
        float4 ur0 = *(const float4*)(ub0 + kc);
        float4 uz0 = *(const float4*)(ub0 + WSTR + kc);
        float4 un0 = *(const float4*)(ub0 + 2 * WSTR + kc);
        float4 wr1 = *(const float4*)(wb1 + kc);
        float4 wz1 = *(const float4*)(wb1 + WSTR + kc);
        float4 wn1 = *(const float4*)(wb1 + 2 * WSTR + kc);
        float4 ur1 = *(const float4*)(ub1 + kc);
        float4 uz1 = *(const float4*)(ub1 + WSTR + kc);
        float4 un1 = *(const float4*)(ub1 + 2 * WSTR + kc);
#pragma unroll
        for (int g = 0; g < 4; ++g) {
            fma4(ar[0][g], wr0, xv[g]);  fma4(ar[0][g], ur0, hv[g]);
            fma4(az[0][g], wz0, xv[g]);  fma4(az[0][g], uz0, hv[g]);
            fma4(anx[0][g], wn0, xv[g]); fma4(anh[0][g], un0, hv[g]);
            fma4(ar[1][g], wr1, xv[g]);  fma4(ar[1][g], ur1, hv[g]);
            fma4(az[1][g], wz1, xv[g]);  fma4(az[1][g], uz1, hv[g]);
            fma4(anx[1][g], wn1, xv[g]); fma4(anh[1][g], un1, hv[g]);
        }
    }
#pragma unroll
    for (int g = 0; g < 4; ++g) {
        float2 ho = *(const float2*)(sh1 + (bl + 16 * g) * LH + jB);
        float hold[2] = {ho.x, ho.y};
#pragma unroll
        for (int jj = 0; jj < 2; ++jj) {
            float r = sigm_(ar[jj][g]);
            float z = sigm_(az[jj][g]);
            float n = tanhf(fmaf(r, anh[jj][g], anx[jj][g]));
            hn[jj][g] = fmaf(z, hold[jj] - n, n);
        }
    }
}

extern "C" __global__ void __launch_bounds__(512, 2)
ccseq_kernel(const float* __restrict__ x, const int* __restrict__ p_tlen,
             const float* __restrict__ eW0, const float* __restrict__ eU0,
             const float* __restrict__ eBi0, const float* __restrict__ eBh0,
             const float* __restrict__ eW1, const float* __restrict__ eU1,
             const float* __restrict__ eBi1, const float* __restrict__ eBh1,
             const float* __restrict__ dW0, const float* __restrict__ dU0,
             const float* __restrict__ dBi0, const float* __restrict__ dBh0,
             const float* __restrict__ dW1, const float* __restrict__ dU1,
             const float* __restrict__ dBi1, const float* __restrict__ dBh1,
             const float* __restrict__ Won, const float* __restrict__ bon,
             const float* __restrict__ Wcv, const float* __restrict__ bcv,
             float* __restrict__ out)
{
    const int tid  = threadIdx.x;
    const int lane = tid & 63;
    const int wv   = tid >> 6;          // 0..7
    const int jg   = lane >> 4;         // 0..3
    const int bl   = lane & 15;         // 0..15
    const int jB   = wv * 8 + jg * 2;   // this lane's 2 hidden units
    const int tlen = p_tlen[0];

    if (tid < 64) { sHd[tid] = Wcv[tid]; sHd[64 + tid] = Won[tid]; }
    for (int i = tid; i < 64 * LH; i += 512) { sh0[i] = 0.0f; sh1[i] = 0.0f; }
    stage_w1(eW1, eU1);
    __syncthreads();

    // ---- hoisted per-lane constants (encoder) ----
    float w0r[2 * NIE], w0z[2 * NIE], w0n[2 * NIE];
#pragma unroll
    for (int jj = 0; jj < 2; ++jj)
#pragma unroll
        for (int k = 0; k < NIE; ++k) {
            w0r[jj * NIE + k] = eW0[(jB + jj) * NIE + k];
            w0z[jj * NIE + k] = eW0[(64 + jB + jj) * NIE + k];
            w0n[jj * NIE + k] = eW0[(128 + jB + jj) * NIE + k];
        }
    float eb_r[2], eb_z[2], eb_nx[2], eb_nh[2];
    float e1_r[2], e1_z[2], e1_nx[2], e1_nh[2];
#pragma unroll
    for (int jj = 0; jj < 2; ++jj) {
        int j = jB + jj;
        eb_r[jj]  = eBi0[j] + eBh0[j];
        eb_z[jj]  = eBi0[64 + j] + eBh0[64 + j];
        eb_nx[jj] = eBi0[128 + j];
        eb_nh[jj] = eBh0[128 + j];
        e1_r[jj]  = eBi1[j] + eBh1[j];
        e1_z[jj]  = eBi1[64 + j] + eBh1[64 + j];
        e1_nx[jj] = eBi1[128 + j];
        e1_nh[jj] = eBh1[128 + j];
    }

    const size_t bstr = (size_t)TENC * NIE;
    const float* xb[4];
#pragma unroll
    for (int g = 0; g < 4; ++g)
        xb[g] = x + (size_t)(blockIdx.x * 64 + bl + 16 * g) * bstr;

    // ---------------- encoder ----------------
    float xc[4 * NIE], xn[4 * NIE];
#pragma unroll
    for (int g = 0; g < 4; ++g)
#pragma unroll
        for (int k = 0; k < NIE; ++k) xc[g * NIE + k] = xb[g][k];

    for (int t = 0; t < TENC; ++t) {
        const int tn = (t + 1 < TENC) ? (t + 1) : t;
#pragma unroll
        for (int g = 0; g < 4; ++g)
#pragma unroll
            for (int k = 0; k < NIE; ++k) xn[g * NIE + k] = xb[g][tn * NIE + k];

        float hn[2][4];
        layer0_c<NIE>(eU0, w0r, w0z, w0n, xc, eb_r, eb_z, eb_nx, eb_nh, jB, bl, hn);
        __syncthreads();                       // all sh0 reads done
#pragma unroll
        for (int g = 0; g < 4; ++g)
            *(float2*)(sh0 + (bl + 16 * g) * LH + jB) = make_float2(hn[0][g], hn[1][g]);
        __syncthreads();                       // h0_new published

        layer1_c(e1_r, e1_z, e1_nx, e1_nh, jB, bl, hn);
        __syncthreads();                       // all sh1 reads done
#pragma unroll
        for (int g = 0; g < 4; ++g)
            *(float2*)(sh1 + (bl + 16 * g) * LH + jB) = make_float2(hn[0][g], hn[1][g]);
        __syncthreads();                       // h1_new published

#pragma unroll
        for (int i = 0; i < 4 * NIE; ++i) xc[i] = xn[i];
    }

    // ---------------- swap to decoder weights ----------------
    stage_w1(dW1, dU1);                        // safe: barrier above drained reads
    float v0r[2], v0z[2], v0n[2];
    float db_r[2], db_z[2], db_nx[2], db_nh[2];
    float d1_r[2], d1_z[2], d1_nx[2], d1_nh[2];
#pragma unroll
    for (int jj = 0; jj < 2; ++jj) {
        int j = jB + jj;
        v0r[jj] = dW0[j]; v0z[jj] = dW0[64 + j]; v0n[jj] = dW0[128 + j];
        db_r[jj]  = dBi0[j] + dBh0[j];
        db_z[jj]  = dBi0[64 + j] + dBh0[64 + j];
        db_nx[jj] = dBi0[128 + j];
        db_nh[jj] = dBh0[128 + j];
        d1_r[jj]  = dBi1[j] + dBh1[j];
        d1_z[jj]  = dBi1[64 + j] + dBh1[64 + j];
        d1_nx[jj] = dBi1[128 + j];
        d1_nh[jj] = dBh1[128 + j];
    }
    const float hbc = bcv[0], hbo = bon[0];
    __syncthreads();

    // ---------------- decoder ----------------
    float prev[4] = {0.0f, 0.0f, 0.0f, 0.0f};
    for (int t = 0; t < tlen; ++t) {
        float hn[2][4];
        layer0_c<1>(dU0, v0r, v0z, v0n, prev, db_r, db_z, db_nx, db_nh, jB, bl, hn);
        __syncthreads();
#pragma unroll
        for (int g = 0; g < 4; ++g)
            *(float2*)(sh0 + (bl + 16 * g) * LH + jB) = make_float2(hn[0][g], hn[1][g]);
        __syncthreads();

        layer1_c(d1_r, d1_z, d1_nx, d1_nh, jB, bl, hn);
        __syncthreads();
#pragma unroll
        for (int g = 0; g < 4; ++g)
            *(float2*)(sh1 + (bl + 16 * g) * LH + jB) = make_float2(hn[0][g], hn[1][g]);
        __syncthreads();                       // full h1_new readable

        // heads: every lane computes its own 4 batches (no exchange needed)
        float cv[4] = {hbc, hbc, hbc, hbc};
        float lg[4] = {hbo, hbo, hbo, hbo};
        const float* hr0 = sh1 + bl * LH;
#pragma unroll 2
        for (int kc = 0; kc < 64; kc += 4) {
            float4 wc = *(const float4*)(sHd + kc);
            float4 wo = *(const float4*)(sHd + 64 + kc);
#pragma unroll
            for (int g = 0; g < 4; ++g) {
                float4 h4 = *(const float4*)(hr0 + g * (16 * LH) + kc);
                fma4(cv[g], wc, h4);
                fma4(lg[g], wo, h4);
            }
        }
#pragma unroll
        for (int g = 0; g < 4; ++g)
            prev[g] = (lg[g] > 0.0f) ? cv[g] : 0.0f;   // sigmoid(lg)>0.5 <=> lg>0
        if (tid < 16) {
#pragma unroll
            for (int g = 0; g < 4; ++g)
                out[(size_t)(blockIdx.x * 64 + bl + 16 * g) * tlen + t] = prev[g];
        }
    }
}

extern "C" void kernel_launch(void* const* d_in, const int* in_sizes, int n_in,
                              void* d_out, int out_size, void* d_ws, size_t ws_size,
                              hipStream_t stream)
{
    (void)n_in; (void)out_size; (void)d_ws; (void)ws_size;
    const float* x    = (const float*)d_in[0];
    const int*   tl   = (const int*)d_in[1];
    const float* eW0  = (const float*)d_in[2];
    const float* eU0  = (const float*)d_in[3];
    const float* eBi0 = (const float*)d_in[4];
    const float* eBh0 = (const float*)d_in[5];
    const float* eW1  = (const float*)d_in[6];
    const float* eU1  = (const float*)d_in[7];
    const float* eBi1 = (const float*)d_in[8];
    const float* eBh1 = (const float*)d_in[9];
    const float* dW0  = (const float*)d_in[10];
    const float* dU0  = (const float*)d_in[11];
    const float* dBi0 = (const float*)d_in[12];
    const float* dBh0 = (const float*)d_in[13];
    const float* dW1  = (const float*)d_in[14];
    const float* dU1  = (const float*)d_in[15];
    const float* dBi1 = (const float*)d_in[16];
    const float* dBh1 = (const float*)d_in[17];
    const float* Won  = (const float*)d_in[18];
    const float* bon  = (const float*)d_in[19];
    const float* Wcv  = (const float*)d_in[20];
    const float* bcv  = (const float*)d_in[21];

    const int B    = in_sizes[0] / (TENC * NIE);  // 16384
    const int nblk = B / 64;                      // 256 blocks, 1/CU

    ccseq_kernel<<<dim3(nblk), dim3(512), 0, stream>>>(
        x, tl, eW0, eU0, eBi0, eBh0, eW1, eU1, eBi1, eBh1,
        dW0, dU0, dBi0, dBh0, dW1, dU1, dBi1, dBh1,
        Won, bon, Wcv, bcv, (float*)d_out);
}